// Round 16
// baseline (314.895 us; speedup 1.0000x reference)
//
#include <hip/hip_runtime.h>
#include <math.h>

// x: [8,512,32,32] fp32 | W_qkv: [1536,512,3,3] fp32 | W_out: [512,512,1,1]
// gamma/beta: [512] | out: [8,512,32,32] fp32
// G=8 heads, D=64 head dim, N=1024 seq (h*w), B=8

#define SMOOTH 1e-4f
#define BN_EPS 1e-5f

typedef __attribute__((ext_vector_type(8))) short bf16x8;
typedef __attribute__((ext_vector_type(8))) unsigned short u16x8;
typedef __attribute__((ext_vector_type(4))) float f32x4;
typedef __attribute__((ext_vector_type(4))) unsigned int u32x4;
typedef __attribute__((ext_vector_type(4))) unsigned short u16x4;

__device__ inline unsigned short bf16rne(float f) {
  unsigned int u = __float_as_uint(f);
  u += 0x7fff + ((u >> 16) & 1);
  return (unsigned short)(u >> 16);
}
__device__ inline float b2f(unsigned short u) {
  return __uint_as_float((unsigned int)u << 16);
}

// Async 16B global->LDS DMA (gfx950). LDS dest = wave-uniform base + lane*16.
// RULE (R8): lane gptr MUST be base + lane*16 (contiguous 1KB/wave),
// else ~4-5x HBM overfetch.
typedef __attribute__((address_space(1))) void gvoid;
typedef __attribute__((address_space(3))) void lvoid;
__device__ __forceinline__ void async16(const void* g, void* l) {
  __builtin_amdgcn_global_load_lds((gvoid*)g, (lvoid*)l, 16, 0, 0);
}

// ---------------------------------------------------------------------------
// prep_kernel: merged repacks (unchanged from R15).
// ---------------------------------------------------------------------------
__global__ void prep_kernel(const float* __restrict__ wq,
                            unsigned short* __restrict__ wqr2,
                            const float* __restrict__ x,
                            unsigned short* __restrict__ xrp2,
                            const float* __restrict__ wo,
                            unsigned short* __restrict__ wor,
                            float* __restrict__ sums,
                            float* __restrict__ sumsq) {
  __shared__ float Sh[32 * 292];  // W: 32 rows x 288 (pad 292); X: 64 x 132
  const int tid = threadIdx.x;
  const int bid = blockIdx.x;
  if (bid < 768) {
    // ---- repack W_qkv (coalesced both sides) ----
    const int cotile = bid / 32;
    const int rem = bid - cotile * 32;
    const int ci0c = rem >> 1, cohalf = rem & 1;
#pragma unroll
    for (int k = 0; k < 9; ++k) {
      int idx = tid + k * 256;
      int row = idx / 72, col = idx - row * 72;
      *(float4*)(Sh + row * 292 + col * 4) =
          *(const float4*)(wq +
                           (size_t)(cotile * 64 + cohalf * 32 + row) * 4608 +
                           ci0c * 288 + col * 4);
    }
    __syncthreads();
    const size_t wbase = (size_t)(ci0c * 24 + cotile) * 18432;
#pragma unroll
    for (int k = 0; k < 5; ++k) {
      int j = tid + k * 256;
      if (j < 1152) {
        int co_l = j & 31;
        int g36 = j >> 5;  // 0..35
        int c4 = g36 / 9, tt = g36 - c4 * 9;
        u16x8 pk;
#pragma unroll
        for (int e = 0; e < 8; ++e)
          pk[e] = bf16rne(Sh[co_l * 292 + (c4 * 8 + e) * 9 + tt]);
        *(u16x8*)(wqr2 + wbase +
                  (size_t)((c4 * 9 + tt) * 64 + cohalf * 32 + co_l) * 8) = pk;
      }
    }
  } else if (bid < 1280) {
    // ---- repack x (LDS tile transpose) ----
    const int bx = bid - 768;
    const int p0 = (bx & 7) * 128;
    const int ci0 = ((bx >> 3) & 7) * 64;
    const int b = bx >> 6;
    for (int k = 0; k < 8; ++k) {
      int idx = tid + k * 256;
      int c4 = idx & 31, row = idx >> 5;
      *(float4*)(Sh + row * 132 + c4 * 4) =
          *(const float4*)(x + ((size_t)(b * 512 + ci0 + row)) * 1024 + p0 + c4 * 4);
    }
    __syncthreads();
    const int pl = tid >> 1, half = tid & 1;
    const int p = p0 + pl;
    const int h = p >> 5, w = p & 31;
#pragma unroll
    for (int v = 0; v < 8; ++v) {
      u16x4 pk;
#pragma unroll
      for (int e = 0; e < 4; ++e)
        pk[e] = bf16rne(Sh[(half * 32 + v * 4 + e) * 132 + pl]);
      int cc = ci0 + half * 32 + v * 4;
      int ci0c = cc >> 5, c4 = (cc >> 3) & 3, e0 = cc & 7;
      size_t gran =
          (size_t)((ci0c * 4 + c4) * 8 + b) * 1156 + (h + 1) * 34 + (w + 1);
      *(u16x4*)(xrp2 + gran * 8 + e0) = pk;
    }
  } else {
    // ---- repack W_out + zero stats ----
    const int rb = bid - 1280;
    int idx = rb * 256 + tid;
    wor[idx] = bf16rne(wo[idx]);
    if (rb < 2) {
      sums[idx] = 0.f;
      sumsq[idx] = 0.f;
    }
  }
}

// ---------------------------------------------------------------------------
// Kernel 1: 3x3 conv bf16 MFMA implicit GEMM — R10/R13 version VERBATIM
// (measured optimum: 107us, MfmaUtil 50%, 0 bank conflicts, LDS-port bound).
// ---------------------------------------------------------------------------
__global__ __launch_bounds__(256) void conv3x3_mfma(
    const unsigned short* __restrict__ wqr2,
    const unsigned short* __restrict__ xrp2,
    unsigned short* __restrict__ qt, unsigned short* __restrict__ kt,
    unsigned short* __restrict__ vt, float* __restrict__ rqn,
    float* __restrict__ rkn) {
  __shared__ __align__(16) unsigned short Wl[2304 * 8];     // 36864 B
  __shared__ __align__(16) unsigned short Xl[4 * 256 * 8];  // 16384 B
  __shared__ float Snl[128];                                // norm partials

  const int tid = threadIdx.x;
  const int lane = tid & 63;
  const int wave = tid >> 6;
  const int wco = (wave & 1) * 32;
  const int wn = (wave >> 1) * 64;
  const int l15 = lane & 15;
  const int quad = lane >> 4;
  const int h0 = blockIdx.x * 4;
  const int co0 = blockIdx.y * 64;
  const int b = blockIdx.z;

  f32x4 acc[2][4];
  for (int ma = 0; ma < 2; ++ma)
    for (int nb = 0; nb < 4; ++nb) acc[ma][nb] = (f32x4){0.f, 0.f, 0.f, 0.f};

  for (int ci0 = 0; ci0 < 512; ci0 += 32) {
    const int ci0c = ci0 >> 5;
    __syncthreads();  // prior iter's readers done
    const unsigned short* wsrc =
        wqr2 + (size_t)(ci0c * 24 + (co0 >> 6)) * 18432;
    {
      int cbase = wave * 9;
#pragma unroll
      for (int j = 0; j < 9; ++j) {
        int c = cbase + j;
        async16(wsrc + (size_t)c * 512 + lane * 8, Wl + (size_t)c * 512);
      }
    }
    const unsigned short* xsrc =
        xrp2 + ((size_t)((ci0c * 4 + wave) * 8 + b) * 1156 + h0 * 34) * 8;
#pragma unroll
    for (int j = 0; j < 4; ++j)
      async16(xsrc + (size_t)j * 512 + lane * 8,
              Xl + (size_t)(wave * 256 + j * 64) * 8);
    __syncthreads();  // drains vmcnt before frag reads

#pragma unroll
    for (int t = 0; t < 9; ++t) {
      const int ky = t / 3, kx = t - ky * 3;
      bf16x8 af[2], bfr[4];
#pragma unroll
      for (int ma = 0; ma < 2; ++ma)
        af[ma] = *(const bf16x8*)(
            Wl + (size_t)((quad * 9 + t) * 64 + wco + ma * 16 + l15) * 8);
#pragma unroll
      for (int nb = 0; nb < 4; ++nb) {
        int n = wn + nb * 16 + l15;
        int hh = (n >> 5) + ky;
        int wi = (n & 31) + kx;
        bfr[nb] = *(const bf16x8*)(Xl + (size_t)(quad * 256 + hh * 34 + wi) * 8);
      }
#pragma unroll
      for (int ma = 0; ma < 2; ++ma)
#pragma unroll
        for (int nb = 0; nb < 4; ++nb)
          acc[ma][nb] = __builtin_amdgcn_mfma_f32_16x16x32_bf16(
              af[ma], bfr[nb], acc[ma][nb], 0, 0, 0);
    }
  }

  const int sec = co0 >> 9;
  const int g = (co0 & 511) >> 6;
  const int bg = b * 8 + g;
  if (sec < 2) {
    unsigned short* dst = (sec == 0) ? qt : kt;
#pragma unroll
    for (int ma = 0; ma < 2; ++ma)
#pragma unroll
      for (int nb = 0; nb < 4; ++nb) {
        int n = wn + nb * 16 + l15;
        int p = (h0 + (n >> 5)) * 32 + (n & 31);
        int db = wco + ma * 16 + quad * 4;
        u16x4 pk;
#pragma unroll
        for (int r = 0; r < 4; ++r) pk[r] = bf16rne(acc[ma][nb][r]);
        *(u16x4*)(dst + ((size_t)bg * 1024 + p) * 64 + db) = pk;
      }
    float ps[4];
#pragma unroll
    for (int nb = 0; nb < 4; ++nb) {
      float s = 0.f;
#pragma unroll
      for (int ma = 0; ma < 2; ++ma)
#pragma unroll
        for (int r = 0; r < 4; ++r) s = fmaf(acc[ma][nb][r], acc[ma][nb][r], s);
      s += __shfl_down(s, 32);
      s += __shfl_down(s, 16);
      ps[nb] = s;  // valid in quad==0 lanes
    }
    if (wco == 0 && quad == 0)
#pragma unroll
      for (int nb = 0; nb < 4; ++nb) Snl[wn + nb * 16 + l15] = ps[nb];
    __syncthreads();
    if (wco == 32 && quad == 0) {
      float* ndst = (sec == 0) ? rqn : rkn;
#pragma unroll
      for (int nb = 0; nb < 4; ++nb) {
        int n = wn + nb * 16 + l15;
        int p = (h0 + (n >> 5)) * 32 + (n & 31);
        ndst[bg * 1024 + p] = rsqrtf(Snl[n] + ps[nb] + SMOOTH);
      }
    }
  } else {
#pragma unroll
    for (int ma = 0; ma < 2; ++ma)
#pragma unroll
      for (int nb = 0; nb < 4; ++nb) {
        int n = wn + nb * 16 + l15;
        int p = (h0 + (n >> 5)) * 32 + (n & 31);
#pragma unroll
        for (int r = 0; r < 4; ++r) {
          int d = wco + ma * 16 + quad * 4 + r;
          vt[((size_t)bg * 64 + d) * 1024 + p] = bf16rne(acc[ma][nb][r]);
        }
      }
  }
}

// ---------------------------------------------------------------------------
// Kernel 3: attention — SINGLE WAVE per block (R16). Wave owns 64 i-rows.
// Zero __syncthreads: within one wave DS ops execute in order, so
// K-read -> S-overwrite (same LDS region) and S-read -> next-K-write are
// automatically ordered. S aliases the K region: LDS 18.3KB -> 8 blocks/CU.
// Per jt: 16 global loads -> 16 ds_writes -> GEMM1 (32 MFMA) -> S pack
// (16 u16x4) -> GEMM2 (32 MFMA). Compiler can hoist jt+1 loads over GEMM2.
// K staged at perm(j)=(j&3)*16+(j>>2) rows (stride 74, breaks write-bank
// alignment); S lands in linear-j columns matching V's linear-j contraction.
// ---------------------------------------------------------------------------
__global__ __launch_bounds__(64) void attn_mfma(
    const unsigned short* __restrict__ qt, const unsigned short* __restrict__ kt,
    const unsigned short* __restrict__ vt, const float* __restrict__ rqn,
    const float* __restrict__ rkn, unsigned short* __restrict__ aob) {
  __shared__ __align__(16) unsigned short KSl[64 * 74];  // K(perm j) then S[i]
  __shared__ __align__(16) unsigned short Vl[64 * 72];   // [d][j]

  const int lane = threadIdx.x;
  const int l15 = lane & 15, quad = lane >> 4;
  const int bg = blockIdx.x;  // fastest -> same-bg blocks share XCD L2
  const int i0 = blockIdx.y * 64;
  const int b = bg >> 3, g = bg & 7;

  // Staging decode: 8 K + 8 V granules per lane.
  const int c8 = lane & 7;
  const int r0 = lane >> 3;  // rows r0 + 8*s

  bf16x8 qf[4][2];
#pragma unroll
  for (int ma = 0; ma < 4; ++ma)
#pragma unroll
    for (int ks = 0; ks < 2; ++ks)
      qf[ma][ks] = *(const bf16x8*)(
          qt + ((size_t)bg * 1024 + i0 + ma * 16 + l15) * 64 + ks * 32 + quad * 8);

  float rq[4][4];
#pragma unroll
  for (int ma = 0; ma < 4; ++ma)
#pragma unroll
    for (int r = 0; r < 4; ++r)
      rq[ma][r] = rqn[bg * 1024 + i0 + ma * 16 + quad * 4 + r];

  f32x4 oacc[4][4];
  for (int mf = 0; mf < 4; ++mf)
    for (int nf = 0; nf < 4; ++nf) oacc[mf][nf] = (f32x4){0.f, 0.f, 0.f, 0.f};

  for (int jt = 0; jt < 16; ++jt) {
    const int j0 = jt * 64;
    // Stage K (perm rows) + V (linear rows). In-order DS => no barrier.
#pragma unroll
    for (int s = 0; s < 8; ++s) {
      int row = r0 + 8 * s;
      int pr = (row & 3) * 16 + (row >> 2);
      u32x4 kv = *(const u32x4*)(kt + ((size_t)bg * 1024 + j0 + row) * 64 + c8 * 8);
      u32x4 vv = *(const u32x4*)(vt + ((size_t)bg * 64 + row) * 1024 + j0 + c8 * 8);
      *(u32x4*)(KSl + pr * 74 + c8 * 8) = kv;
      *(u32x4*)(Vl + row * 72 + c8 * 8) = vv;
    }

    // GEMM1: S = Q K^T (all kf reads precede S writes in program order).
    f32x4 sacc[4][4];
    for (int ma = 0; ma < 4; ++ma)
      for (int nb = 0; nb < 4; ++nb) sacc[ma][nb] = (f32x4){0.f, 0.f, 0.f, 0.f};
#pragma unroll
    for (int ks = 0; ks < 2; ++ks) {
#pragma unroll
      for (int nb = 0; nb < 4; ++nb) {
        // physical row nb*16+l15 = perm(4*l15+nb): logical j = 4*l15+nb
        bf16x8 kf = *(const bf16x8*)(KSl + (nb * 16 + l15) * 74 + ks * 32 + quad * 8);
#pragma unroll
        for (int ma = 0; ma < 4; ++ma)
          sacc[ma][nb] = __builtin_amdgcn_mfma_f32_16x16x32_bf16(
              qf[ma][ks], kf, sacc[ma][nb], 0, 0, 0);
      }
    }

    // Normalize + pack into KSl (S rows = i, linear-j columns).
    float4 rk4 = *(const float4*)(rkn + bg * 1024 + j0 + 4 * l15);
#pragma unroll
    for (int ma = 0; ma < 4; ++ma)
#pragma unroll
      for (int r = 0; r < 4; ++r) {
        u16x4 pk;
        pk[0] = bf16rne(sacc[ma][0][r] * (rq[ma][r] * rk4.x));
        pk[1] = bf16rne(sacc[ma][1][r] * (rq[ma][r] * rk4.y));
        pk[2] = bf16rne(sacc[ma][2][r] * (rq[ma][r] * rk4.z));
        pk[3] = bf16rne(sacc[ma][3][r] * (rq[ma][r] * rk4.w));
        *(u16x4*)(KSl + (ma * 16 + quad * 4 + r) * 74 + 4 * l15) = pk;
      }

    // GEMM2: O += S V (sa reads precede next jt's K writes in program order).
#pragma unroll
    for (int ks2 = 0; ks2 < 2; ++ks2) {
      bf16x8 sa[4];
#pragma unroll
      for (int mf = 0; mf < 4; ++mf)
        sa[mf] = *(const bf16x8*)(KSl + (mf * 16 + l15) * 74 + ks2 * 32 + quad * 8);
#pragma unroll
      for (int nf = 0; nf < 4; ++nf) {
        bf16x8 vb = *(const bf16x8*)(Vl + (l15 + 16 * nf) * 72 + ks2 * 32 + quad * 8);
#pragma unroll
        for (int mf = 0; mf < 4; ++mf)
          oacc[mf][nf] = __builtin_amdgcn_mfma_f32_16x16x32_bf16(
              sa[mf], vb, oacc[mf][nf], 0, 0, 0);
      }
    }
  }

#pragma unroll
  for (int mf = 0; mf < 4; ++mf)
#pragma unroll
    for (int nf = 0; nf < 4; ++nf)
#pragma unroll
      for (int r = 0; r < 4; ++r) {
        int i = i0 + mf * 16 + quad * 4 + r;
        int d = l15 + 16 * nf;
        aob[((size_t)(b * 1024) + i) * 512 + g * 64 + d] = bf16rne(oacc[mf][nf][r]);
      }
}

// ---------------------------------------------------------------------------
// Kernel 4: 1x1 conv bf16 MFMA (M=512co, N=8192p, K=512ci) + BN stats.
// ---------------------------------------------------------------------------
__global__ __launch_bounds__(256) void conv1x1_mfma(
    const unsigned short* __restrict__ wor, const unsigned short* __restrict__ aob,
    unsigned short* __restrict__ yb, float* __restrict__ sums,
    float* __restrict__ sumsq) {
  __shared__ __align__(16) unsigned short Wl[64 * 40];
  __shared__ __align__(16) unsigned short Bl[64 * 40];

  const int tid = threadIdx.x;
  const int lane = tid & 63, wave = tid >> 6;
  const int l15 = lane & 15, quad = lane >> 4;
  const int wco = (wave & 1) * 32;
  const int wp = (wave >> 1) * 32;
  const int p0 = blockIdx.x * 64;
  const int co0 = blockIdx.y * 64;
  const int b = blockIdx.z;

  f32x4 acc[2][2];
  for (int ma = 0; ma < 2; ++ma)
    for (int nb = 0; nb < 2; ++nb) acc[ma][nb] = (f32x4){0.f, 0.f, 0.f, 0.f};

  for (int ci0 = 0; ci0 < 512; ci0 += 32) {
    __syncthreads();
    {
      int c4 = tid & 3, co = tid >> 2;
      *(u32x4*)(Wl + co * 40 + c4 * 8) =
          *(const u32x4*)(wor + (size_t)(co0 + co) * 512 + ci0 + c4 * 8);
      *(u32x4*)(Bl + co * 40 + c4 * 8) =
          *(const u32x4*)(aob + ((size_t)(b * 1024) + p0 + co) * 512 + ci0 + c4 * 8);
    }
    __syncthreads();

    bf16x8 af[2], bf[2];
#pragma unroll
    for (int ma = 0; ma < 2; ++ma)
      af[ma] = *(const bf16x8*)(Wl + (wco + ma * 16 + l15) * 40 + quad * 8);
#pragma unroll
    for (int nb = 0; nb < 2; ++nb)
      bf[nb] = *(const bf16x8*)(Bl + (wp + nb * 16 + l15) * 40 + quad * 8);
#pragma unroll
    for (int ma = 0; ma < 2; ++ma)
#pragma unroll
      for (int nb = 0; nb < 2; ++nb)
        acc[ma][nb] = __builtin_amdgcn_mfma_f32_16x16x32_bf16(
            af[ma], bf[nb], acc[ma][nb], 0, 0, 0);
  }

#pragma unroll
  for (int ma = 0; ma < 2; ++ma)
#pragma unroll
    for (int r = 0; r < 4; ++r) {
      int co = co0 + wco + ma * 16 + quad * 4 + r;
      float s1 = 0.f, s2 = 0.f;
#pragma unroll
      for (int nb = 0; nb < 2; ++nb) {
        float v = acc[ma][nb][r];
        yb[((size_t)(b * 512) + co) * 1024 + p0 + wp + nb * 16 + l15] = bf16rne(v);
        s1 += v;
        s2 = fmaf(v, v, s2);
      }
      for (int off = 8; off >= 1; off >>= 1) {
        s1 += __shfl_down(s1, off, 16);
        s2 += __shfl_down(s2, off, 16);
      }
      if (l15 == 0) {
        atomicAdd(&sums[co], s1);
        atomicAdd(&sumsq[co], s2);
      }
    }
}

// ---------------------------------------------------------------------------
// Kernel 5: BatchNorm (batch stats, biased var) + ReLU. bf16 in, fp32 out.
// ---------------------------------------------------------------------------
__global__ void bn_kernel(const unsigned short* __restrict__ yb,
                          const float* __restrict__ sums,
                          const float* __restrict__ sumsq,
                          const float* __restrict__ gamma,
                          const float* __restrict__ beta,
                          float* __restrict__ out) {
  int idx = blockIdx.x * 256 + threadIdx.x;
  int c = (idx >> 8) & 511;
  u16x4 vb = *(const u16x4*)(yb + (size_t)idx * 4);
  float mean = sums[c] * (1.f / 8192.f);
  float var = sumsq[c] * (1.f / 8192.f) - mean * mean;
  float sc = gamma[c] * rsqrtf(var + BN_EPS);
  float sh = beta[c] - mean * sc;
  float4 r;
  r.x = fmaxf(0.f, fmaf(b2f(vb[0]), sc, sh));
  r.y = fmaxf(0.f, fmaf(b2f(vb[1]), sc, sh));
  r.z = fmaxf(0.f, fmaf(b2f(vb[2]), sc, sh));
  r.w = fmaxf(0.f, fmaf(b2f(vb[3]), sc, sh));
  ((float4*)out)[idx] = r;
}

// ---------------------------------------------------------------------------
extern "C" void kernel_launch(void* const* d_in, const int* in_sizes, int n_in,
                              void* d_out, int out_size, void* d_ws,
                              size_t ws_size, hipStream_t stream) {
  const float* x = (const float*)d_in[0];
  const float* wq = (const float*)d_in[1];
  const float* wo = (const float*)d_in[2];
  const float* gamma = (const float*)d_in[3];
  const float* beta = (const float*)d_in[4];
  float* out = (float*)d_out;

  unsigned short* qt = (unsigned short*)d_ws;          // [64][1024][64]
  unsigned short* kt = qt + (size_t)4194304;
  unsigned short* vt = kt + (size_t)4194304;           // [64][64][1024]
  unsigned short* aob = vt + (size_t)4194304;          // [8][1024][512]
  unsigned short* wqr2 = aob + (size_t)4194304;        // [16][24][4][9][64][8]
  unsigned short* wor = wqr2 + (size_t)7077888;        // [512][512]
  unsigned short* xrp2 = wor + (size_t)262144;         // [16][4][8][34][34][8]+pad
  float* rqn = (float*)(xrp2 + (size_t)4736000);       // [64][1024]
  float* rkn = rqn + 65536;
  unsigned short* yb = (unsigned short*)(rkn + 65536); // [8][512][1024] bf16
  float* sums = (float*)(yb + (size_t)4194304);
  float* sumsq = sums + 512;

  hipMemsetAsync(xrp2, 0, (size_t)4736000 * 2, stream);
  prep_kernel<<<dim3(2304), 256, 0, stream>>>(wq, wqr2, x, xrp2, wo, wor, sums,
                                              sumsq);
  conv3x3_mfma<<<dim3(8, 24, 8), 256, 0, stream>>>(wqr2, xrp2, qt, kt, vt, rqn,
                                                   rkn);
  attn_mfma<<<dim3(64, 16), 64, 0, stream>>>(qt, kt, vt, rqn, rkn, aob);
  conv1x1_mfma<<<dim3(16, 8, 8), 256, 0, stream>>>(wor, aob, yb, sums, sumsq);
  bn_kernel<<<dim3(4096), 256, 0, stream>>>(yb, sums, sumsq, gamma, beta, out);
}

// Round 17
// 276.836 us; speedup vs baseline: 1.1375x; 1.1375x over previous
//
#include <hip/hip_runtime.h>
#include <math.h>

// x: [8,512,32,32] fp32 | W_qkv: [1536,512,3,3] fp32 | W_out: [512,512,1,1]
// gamma/beta: [512] | out: [8,512,32,32] fp32
// G=8 heads, D=64 head dim, N=1024 seq (h*w), B=8

#define SMOOTH 1e-4f
#define BN_EPS 1e-5f

typedef __attribute__((ext_vector_type(8))) short bf16x8;
typedef __attribute__((ext_vector_type(8))) unsigned short u16x8;
typedef __attribute__((ext_vector_type(4))) float f32x4;
typedef __attribute__((ext_vector_type(4))) unsigned int u32x4;
typedef __attribute__((ext_vector_type(4))) unsigned short u16x4;

__device__ inline unsigned short bf16rne(float f) {
  unsigned int u = __float_as_uint(f);
  u += 0x7fff + ((u >> 16) & 1);
  return (unsigned short)(u >> 16);
}
__device__ inline float b2f(unsigned short u) {
  return __uint_as_float((unsigned int)u << 16);
}

// Async 16B global->LDS DMA (gfx950). LDS dest = wave-uniform base + lane*16.
// RULE (R8): lane gptr MUST be base + lane*16 (contiguous 1KB/wave),
// else ~4-5x HBM overfetch.
typedef __attribute__((address_space(1))) void gvoid;
typedef __attribute__((address_space(3))) void lvoid;
__device__ __forceinline__ void async16(const void* g, void* l) {
  __builtin_amdgcn_global_load_lds((gvoid*)g, (lvoid*)l, 16, 0, 0);
}

// ---------------------------------------------------------------------------
// prep_kernel: merged repacks (R15 version, coalesced W repack).
// ---------------------------------------------------------------------------
__global__ void prep_kernel(const float* __restrict__ wq,
                            unsigned short* __restrict__ wqr2,
                            const float* __restrict__ x,
                            unsigned short* __restrict__ xrp2,
                            const float* __restrict__ wo,
                            unsigned short* __restrict__ wor,
                            float* __restrict__ sums,
                            float* __restrict__ sumsq) {
  __shared__ float Sh[32 * 292];  // W: 32 rows x 288 (pad 292); X: 64 x 132
  const int tid = threadIdx.x;
  const int bid = blockIdx.x;
  if (bid < 768) {
    // ---- repack W_qkv (coalesced both sides) ----
    const int cotile = bid / 32;
    const int rem = bid - cotile * 32;
    const int ci0c = rem >> 1, cohalf = rem & 1;
#pragma unroll
    for (int k = 0; k < 9; ++k) {
      int idx = tid + k * 256;
      int row = idx / 72, col = idx - row * 72;
      *(float4*)(Sh + row * 292 + col * 4) =
          *(const float4*)(wq +
                           (size_t)(cotile * 64 + cohalf * 32 + row) * 4608 +
                           ci0c * 288 + col * 4);
    }
    __syncthreads();
    const size_t wbase = (size_t)(ci0c * 24 + cotile) * 18432;
#pragma unroll
    for (int k = 0; k < 5; ++k) {
      int j = tid + k * 256;
      if (j < 1152) {
        int co_l = j & 31;
        int g36 = j >> 5;  // 0..35
        int c4 = g36 / 9, tt = g36 - c4 * 9;
        u16x8 pk;
#pragma unroll
        for (int e = 0; e < 8; ++e)
          pk[e] = bf16rne(Sh[co_l * 292 + (c4 * 8 + e) * 9 + tt]);
        *(u16x8*)(wqr2 + wbase +
                  (size_t)((c4 * 9 + tt) * 64 + cohalf * 32 + co_l) * 8) = pk;
      }
    }
  } else if (bid < 1280) {
    // ---- repack x (LDS tile transpose) ----
    const int bx = bid - 768;
    const int p0 = (bx & 7) * 128;
    const int ci0 = ((bx >> 3) & 7) * 64;
    const int b = bx >> 6;
    for (int k = 0; k < 8; ++k) {
      int idx = tid + k * 256;
      int c4 = idx & 31, row = idx >> 5;
      *(float4*)(Sh + row * 132 + c4 * 4) =
          *(const float4*)(x + ((size_t)(b * 512 + ci0 + row)) * 1024 + p0 + c4 * 4);
    }
    __syncthreads();
    const int pl = tid >> 1, half = tid & 1;
    const int p = p0 + pl;
    const int h = p >> 5, w = p & 31;
#pragma unroll
    for (int v = 0; v < 8; ++v) {
      u16x4 pk;
#pragma unroll
      for (int e = 0; e < 4; ++e)
        pk[e] = bf16rne(Sh[(half * 32 + v * 4 + e) * 132 + pl]);
      int cc = ci0 + half * 32 + v * 4;
      int ci0c = cc >> 5, c4 = (cc >> 3) & 3, e0 = cc & 7;
      size_t gran =
          (size_t)((ci0c * 4 + c4) * 8 + b) * 1156 + (h + 1) * 34 + (w + 1);
      *(u16x4*)(xrp2 + gran * 8 + e0) = pk;
    }
  } else {
    // ---- repack W_out + zero stats ----
    const int rb = bid - 1280;
    int idx = rb * 256 + tid;
    wor[idx] = bf16rne(wo[idx]);
    if (rb < 2) {
      sums[idx] = 0.f;
      sumsq[idx] = 0.f;
    }
  }
}

// ---------------------------------------------------------------------------
// Kernel 1: 3x3 conv bf16 MFMA implicit GEMM — R10/R13 version VERBATIM
// (measured optimum: 107us, MfmaUtil 50%, 0 bank conflicts, LDS-port bound).
// ---------------------------------------------------------------------------
__global__ __launch_bounds__(256) void conv3x3_mfma(
    const unsigned short* __restrict__ wqr2,
    const unsigned short* __restrict__ xrp2,
    unsigned short* __restrict__ qt, unsigned short* __restrict__ kt,
    unsigned short* __restrict__ vt, float* __restrict__ rqn,
    float* __restrict__ rkn) {
  __shared__ __align__(16) unsigned short Wl[2304 * 8];     // 36864 B
  __shared__ __align__(16) unsigned short Xl[4 * 256 * 8];  // 16384 B
  __shared__ float Snl[128];                                // norm partials

  const int tid = threadIdx.x;
  const int lane = tid & 63;
  const int wave = tid >> 6;
  const int wco = (wave & 1) * 32;
  const int wn = (wave >> 1) * 64;
  const int l15 = lane & 15;
  const int quad = lane >> 4;
  const int h0 = blockIdx.x * 4;
  const int co0 = blockIdx.y * 64;
  const int b = blockIdx.z;

  f32x4 acc[2][4];
  for (int ma = 0; ma < 2; ++ma)
    for (int nb = 0; nb < 4; ++nb) acc[ma][nb] = (f32x4){0.f, 0.f, 0.f, 0.f};

  for (int ci0 = 0; ci0 < 512; ci0 += 32) {
    const int ci0c = ci0 >> 5;
    __syncthreads();  // prior iter's readers done
    const unsigned short* wsrc =
        wqr2 + (size_t)(ci0c * 24 + (co0 >> 6)) * 18432;
    {
      int cbase = wave * 9;
#pragma unroll
      for (int j = 0; j < 9; ++j) {
        int c = cbase + j;
        async16(wsrc + (size_t)c * 512 + lane * 8, Wl + (size_t)c * 512);
      }
    }
    const unsigned short* xsrc =
        xrp2 + ((size_t)((ci0c * 4 + wave) * 8 + b) * 1156 + h0 * 34) * 8;
#pragma unroll
    for (int j = 0; j < 4; ++j)
      async16(xsrc + (size_t)j * 512 + lane * 8,
              Xl + (size_t)(wave * 256 + j * 64) * 8);
    __syncthreads();  // drains vmcnt before frag reads

#pragma unroll
    for (int t = 0; t < 9; ++t) {
      const int ky = t / 3, kx = t - ky * 3;
      bf16x8 af[2], bfr[4];
#pragma unroll
      for (int ma = 0; ma < 2; ++ma)
        af[ma] = *(const bf16x8*)(
            Wl + (size_t)((quad * 9 + t) * 64 + wco + ma * 16 + l15) * 8);
#pragma unroll
      for (int nb = 0; nb < 4; ++nb) {
        int n = wn + nb * 16 + l15;
        int hh = (n >> 5) + ky;
        int wi = (n & 31) + kx;
        bfr[nb] = *(const bf16x8*)(Xl + (size_t)(quad * 256 + hh * 34 + wi) * 8);
      }
#pragma unroll
      for (int ma = 0; ma < 2; ++ma)
#pragma unroll
        for (int nb = 0; nb < 4; ++nb)
          acc[ma][nb] = __builtin_amdgcn_mfma_f32_16x16x32_bf16(
              af[ma], bfr[nb], acc[ma][nb], 0, 0, 0);
    }
  }

  const int sec = co0 >> 9;
  const int g = (co0 & 511) >> 6;
  const int bg = b * 8 + g;
  if (sec < 2) {
    unsigned short* dst = (sec == 0) ? qt : kt;
#pragma unroll
    for (int ma = 0; ma < 2; ++ma)
#pragma unroll
      for (int nb = 0; nb < 4; ++nb) {
        int n = wn + nb * 16 + l15;
        int p = (h0 + (n >> 5)) * 32 + (n & 31);
        int db = wco + ma * 16 + quad * 4;
        u16x4 pk;
#pragma unroll
        for (int r = 0; r < 4; ++r) pk[r] = bf16rne(acc[ma][nb][r]);
        *(u16x4*)(dst + ((size_t)bg * 1024 + p) * 64 + db) = pk;
      }
    float ps[4];
#pragma unroll
    for (int nb = 0; nb < 4; ++nb) {
      float s = 0.f;
#pragma unroll
      for (int ma = 0; ma < 2; ++ma)
#pragma unroll
        for (int r = 0; r < 4; ++r) s = fmaf(acc[ma][nb][r], acc[ma][nb][r], s);
      s += __shfl_down(s, 32);
      s += __shfl_down(s, 16);
      ps[nb] = s;  // valid in quad==0 lanes
    }
    if (wco == 0 && quad == 0)
#pragma unroll
      for (int nb = 0; nb < 4; ++nb) Snl[wn + nb * 16 + l15] = ps[nb];
    __syncthreads();
    if (wco == 32 && quad == 0) {
      float* ndst = (sec == 0) ? rqn : rkn;
#pragma unroll
      for (int nb = 0; nb < 4; ++nb) {
        int n = wn + nb * 16 + l15;
        int p = (h0 + (n >> 5)) * 32 + (n & 31);
        ndst[bg * 1024 + p] = rsqrtf(Snl[n] + ps[nb] + SMOOTH);
      }
    }
  } else {
#pragma unroll
    for (int ma = 0; ma < 2; ++ma)
#pragma unroll
      for (int nb = 0; nb < 4; ++nb) {
        int n = wn + nb * 16 + l15;
        int p = (h0 + (n >> 5)) * 32 + (n & 31);
#pragma unroll
        for (int r = 0; r < 4; ++r) {
          int d = wco + ma * 16 + quad * 4 + r;
          vt[((size_t)bg * 64 + d) * 1024 + p] = bf16rne(acc[ma][nb][r]);
        }
      }
  }
}

// ---------------------------------------------------------------------------
// Kernel 3: attention — R15 version VERBATIM (measured best: 2 waves x 32i,
// K perm, register double-buffered K/V staging, 2 barriers/jt). R16's
// barrier-free single-wave variant regressed (latency exposed with no
// co-resident waves to hide it) — multi-wave + barriers wins here.
// ---------------------------------------------------------------------------
__global__ __launch_bounds__(128) void attn_mfma(
    const unsigned short* __restrict__ qt, const unsigned short* __restrict__ kt,
    const unsigned short* __restrict__ vt, const float* __restrict__ rqn,
    const float* __restrict__ rkn, unsigned short* __restrict__ aob) {
  __shared__ __align__(16) unsigned short Kl[64 * 72];  // [perm(j)][d]
  __shared__ __align__(16) unsigned short Vl[64 * 72];  // [d][j]
  __shared__ __align__(16) unsigned short Sl[64 * 72];  // [i][j], 32 rows/wave

  const int tid = threadIdx.x;
  const int lane = tid & 63, wave = tid >> 6;  // wave 0..1
  const int l15 = lane & 15, quad = lane >> 4;
  const int bg = blockIdx.x;  // fastest -> same-bg blocks share XCD L2
  const int i0 = blockIdx.y * 64;
  const int iw = i0 + wave * 32;
  const int b = bg >> 3, g = bg & 7;

  // Staging decode: 4 K granules + 4 V granules per thread.
  int srow[4], sperm[4], sc8[4];
#pragma unroll
  for (int s = 0; s < 4; ++s) {
    int gidx = tid + s * 128;
    sc8[s] = gidx & 7;
    srow[s] = gidx >> 3;  // 0..63
    sperm[s] = (srow[s] & 3) * 16 + (srow[s] >> 2);
  }

  bf16x8 qf[2][2];
#pragma unroll
  for (int ma = 0; ma < 2; ++ma)
#pragma unroll
    for (int ks = 0; ks < 2; ++ks)
      qf[ma][ks] = *(const bf16x8*)(
          qt + ((size_t)bg * 1024 + iw + ma * 16 + l15) * 64 + ks * 32 + quad * 8);

  float rq[2][4];
#pragma unroll
  for (int ma = 0; ma < 2; ++ma)
#pragma unroll
    for (int r = 0; r < 4; ++r)
      rq[ma][r] = rqn[bg * 1024 + iw + ma * 16 + quad * 4 + r];

  f32x4 oacc[2][4];
  for (int mf = 0; mf < 2; ++mf)
    for (int nf = 0; nf < 4; ++nf) oacc[mf][nf] = (f32x4){0.f, 0.f, 0.f, 0.f};

  unsigned short* Sw = Sl + wave * 32 * 72;

  // Register prefetch of jt=0.
  u32x4 rk[4], rv[4];
#pragma unroll
  for (int s = 0; s < 4; ++s) {
    rk[s] = *(const u32x4*)(kt + ((size_t)bg * 1024 + srow[s]) * 64 + sc8[s] * 8);
    rv[s] = *(const u32x4*)(vt + ((size_t)bg * 64 + srow[s]) * 1024 + sc8[s] * 8);
  }

  for (int jt = 0; jt < 16; ++jt) {
    const int j0 = jt * 64;
    __syncthreads();  // prior iter's LDS reads done
#pragma unroll
    for (int s = 0; s < 4; ++s) {
      *(u32x4*)(Kl + sperm[s] * 72 + sc8[s] * 8) = rk[s];
      *(u32x4*)(Vl + srow[s] * 72 + sc8[s] * 8) = rv[s];
    }
    u32x4 nk[4], nv[4];
    if (jt < 15) {
      const int j1 = j0 + 64;
#pragma unroll
      for (int s = 0; s < 4; ++s) {
        nk[s] = *(const u32x4*)(kt + ((size_t)bg * 1024 + j1 + srow[s]) * 64 + sc8[s] * 8);
        nv[s] = *(const u32x4*)(vt + ((size_t)bg * 64 + srow[s]) * 1024 + j1 + sc8[s] * 8);
      }
    }
    __syncthreads();

    f32x4 sacc[2][4];
    for (int ma = 0; ma < 2; ++ma)
      for (int nb = 0; nb < 4; ++nb) sacc[ma][nb] = (f32x4){0.f, 0.f, 0.f, 0.f};
#pragma unroll
    for (int ks = 0; ks < 2; ++ks) {
#pragma unroll
      for (int nb = 0; nb < 4; ++nb) {
        // physical row nb*16+l15 = perm(4*l15+nb): logical j = 4*l15+nb
        bf16x8 kf = *(const bf16x8*)(Kl + (nb * 16 + l15) * 72 + ks * 32 + quad * 8);
#pragma unroll
        for (int ma = 0; ma < 2; ++ma)
          sacc[ma][nb] = __builtin_amdgcn_mfma_f32_16x16x32_bf16(
              qf[ma][ks], kf, sacc[ma][nb], 0, 0, 0);
      }
    }

    // Normalize + pack: lane holds S[ma*16+quad*4+r][4*l15+nb].
    float4 rk4 = *(const float4*)(rkn + bg * 1024 + j0 + 4 * l15);
#pragma unroll
    for (int ma = 0; ma < 2; ++ma)
#pragma unroll
      for (int r = 0; r < 4; ++r) {
        u16x4 pk;
        pk[0] = bf16rne(sacc[ma][0][r] * (rq[ma][r] * rk4.x));
        pk[1] = bf16rne(sacc[ma][1][r] * (rq[ma][r] * rk4.y));
        pk[2] = bf16rne(sacc[ma][2][r] * (rq[ma][r] * rk4.z));
        pk[3] = bf16rne(sacc[ma][3][r] * (rq[ma][r] * rk4.w));
        *(u16x4*)(Sw + (ma * 16 + quad * 4 + r) * 72 + 4 * l15) = pk;
      }
    // Sw is wave-private: lgkmcnt orders write->read, no barrier needed.
#pragma unroll
    for (int ks2 = 0; ks2 < 2; ++ks2) {
      bf16x8 sa[2];
#pragma unroll
      for (int mf = 0; mf < 2; ++mf)
        sa[mf] = *(const bf16x8*)(Sw + (mf * 16 + l15) * 72 + ks2 * 32 + quad * 8);
#pragma unroll
      for (int nf = 0; nf < 4; ++nf) {
        bf16x8 vb = *(const bf16x8*)(Vl + (l15 + 16 * nf) * 72 + ks2 * 32 + quad * 8);
#pragma unroll
        for (int mf = 0; mf < 2; ++mf)
          oacc[mf][nf] = __builtin_amdgcn_mfma_f32_16x16x32_bf16(
              sa[mf], vb, oacc[mf][nf], 0, 0, 0);
      }
    }
    if (jt < 15) {
#pragma unroll
      for (int s = 0; s < 4; ++s) {
        rk[s] = nk[s];
        rv[s] = nv[s];
      }
    }
  }

#pragma unroll
  for (int mf = 0; mf < 2; ++mf)
#pragma unroll
    for (int nf = 0; nf < 4; ++nf)
#pragma unroll
      for (int r = 0; r < 4; ++r) {
        int i = iw + mf * 16 + quad * 4 + r;
        int d = l15 + 16 * nf;
        aob[((size_t)(b * 1024) + i) * 512 + g * 64 + d] = bf16rne(oacc[mf][nf][r]);
      }
}

// ---------------------------------------------------------------------------
// Kernel 4: 1x1 conv bf16 MFMA (M=512co, N=8192p, K=512ci) + BN stats.
// ---------------------------------------------------------------------------
__global__ __launch_bounds__(256) void conv1x1_mfma(
    const unsigned short* __restrict__ wor, const unsigned short* __restrict__ aob,
    unsigned short* __restrict__ yb, float* __restrict__ sums,
    float* __restrict__ sumsq) {
  __shared__ __align__(16) unsigned short Wl[64 * 40];
  __shared__ __align__(16) unsigned short Bl[64 * 40];

  const int tid = threadIdx.x;
  const int lane = tid & 63, wave = tid >> 6;
  const int l15 = lane & 15, quad = lane >> 4;
  const int wco = (wave & 1) * 32;
  const int wp = (wave >> 1) * 32;
  const int p0 = blockIdx.x * 64;
  const int co0 = blockIdx.y * 64;
  const int b = blockIdx.z;

  f32x4 acc[2][2];
  for (int ma = 0; ma < 2; ++ma)
    for (int nb = 0; nb < 2; ++nb) acc[ma][nb] = (f32x4){0.f, 0.f, 0.f, 0.f};

  for (int ci0 = 0; ci0 < 512; ci0 += 32) {
    __syncthreads();
    {
      int c4 = tid & 3, co = tid >> 2;
      *(u32x4*)(Wl + co * 40 + c4 * 8) =
          *(const u32x4*)(wor + (size_t)(co0 + co) * 512 + ci0 + c4 * 8);
      *(u32x4*)(Bl + co * 40 + c4 * 8) =
          *(const u32x4*)(aob + ((size_t)(b * 1024) + p0 + co) * 512 + ci0 + c4 * 8);
    }
    __syncthreads();

    bf16x8 af[2], bf[2];
#pragma unroll
    for (int ma = 0; ma < 2; ++ma)
      af[ma] = *(const bf16x8*)(Wl + (wco + ma * 16 + l15) * 40 + quad * 8);
#pragma unroll
    for (int nb = 0; nb < 2; ++nb)
      bf[nb] = *(const bf16x8*)(Bl + (wp + nb * 16 + l15) * 40 + quad * 8);
#pragma unroll
    for (int ma = 0; ma < 2; ++ma)
#pragma unroll
      for (int nb = 0; nb < 2; ++nb)
        acc[ma][nb] = __builtin_amdgcn_mfma_f32_16x16x32_bf16(
            af[ma], bf[nb], acc[ma][nb], 0, 0, 0);
  }

#pragma unroll
  for (int ma = 0; ma < 2; ++ma)
#pragma unroll
    for (int r = 0; r < 4; ++r) {
      int co = co0 + wco + ma * 16 + quad * 4 + r;
      float s1 = 0.f, s2 = 0.f;
#pragma unroll
      for (int nb = 0; nb < 2; ++nb) {
        float v = acc[ma][nb][r];
        yb[((size_t)(b * 512) + co) * 1024 + p0 + wp + nb * 16 + l15] = bf16rne(v);
        s1 += v;
        s2 = fmaf(v, v, s2);
      }
      for (int off = 8; off >= 1; off >>= 1) {
        s1 += __shfl_down(s1, off, 16);
        s2 += __shfl_down(s2, off, 16);
      }
      if (l15 == 0) {
        atomicAdd(&sums[co], s1);
        atomicAdd(&sumsq[co], s2);
      }
    }
}

// ---------------------------------------------------------------------------
// Kernel 5: BatchNorm (batch stats, biased var) + ReLU. bf16 in, fp32 out.
// ---------------------------------------------------------------------------
__global__ void bn_kernel(const unsigned short* __restrict__ yb,
                          const float* __restrict__ sums,
                          const float* __restrict__ sumsq,
                          const float* __restrict__ gamma,
                          const float* __restrict__ beta,
                          float* __restrict__ out) {
  int idx = blockIdx.x * 256 + threadIdx.x;
  int c = (idx >> 8) & 511;
  u16x4 vb = *(const u16x4*)(yb + (size_t)idx * 4);
  float mean = sums[c] * (1.f / 8192.f);
  float var = sumsq[c] * (1.f / 8192.f) - mean * mean;
  float sc = gamma[c] * rsqrtf(var + BN_EPS);
  float sh = beta[c] - mean * sc;
  float4 r;
  r.x = fmaxf(0.f, fmaf(b2f(vb[0]), sc, sh));
  r.y = fmaxf(0.f, fmaf(b2f(vb[1]), sc, sh));
  r.z = fmaxf(0.f, fmaf(b2f(vb[2]), sc, sh));
  r.w = fmaxf(0.f, fmaf(b2f(vb[3]), sc, sh));
  ((float4*)out)[idx] = r;
}

// ---------------------------------------------------------------------------
extern "C" void kernel_launch(void* const* d_in, const int* in_sizes, int n_in,
                              void* d_out, int out_size, void* d_ws,
                              size_t ws_size, hipStream_t stream) {
  const float* x = (const float*)d_in[0];
  const float* wq = (const float*)d_in[1];
  const float* wo = (const float*)d_in[2];
  const float* gamma = (const float*)d_in[3];
  const float* beta = (const float*)d_in[4];
  float* out = (float*)d_out;

  unsigned short* qt = (unsigned short*)d_ws;          // [64][1024][64]
  unsigned short* kt = qt + (size_t)4194304;
  unsigned short* vt = kt + (size_t)4194304;           // [64][64][1024]
  unsigned short* aob = vt + (size_t)4194304;          // [8][1024][512]
  unsigned short* wqr2 = aob + (size_t)4194304;        // [16][24][4][9][64][8]
  unsigned short* wor = wqr2 + (size_t)7077888;        // [512][512]
  unsigned short* xrp2 = wor + (size_t)262144;         // [16][4][8][34][34][8]+pad
  float* rqn = (float*)(xrp2 + (size_t)4736000);       // [64][1024]
  float* rkn = rqn + 65536;
  unsigned short* yb = (unsigned short*)(rkn + 65536); // [8][512][1024] bf16
  float* sums = (float*)(yb + (size_t)4194304);
  float* sumsq = sums + 512;

  hipMemsetAsync(xrp2, 0, (size_t)4736000 * 2, stream);
  prep_kernel<<<dim3(2304), 256, 0, stream>>>(wq, wqr2, x, xrp2, wo, wor, sums,
                                              sumsq);
  conv3x3_mfma<<<dim3(8, 24, 8), 256, 0, stream>>>(wqr2, xrp2, qt, kt, vt, rqn,
                                                   rkn);
  attn_mfma<<<dim3(64, 16), 128, 0, stream>>>(qt, kt, vt, rqn, rkn, aob);
  conv1x1_mfma<<<dim3(16, 8, 8), 256, 0, stream>>>(wor, aob, yb, sums, sumsq);
  bn_kernel<<<dim3(4096), 256, 0, stream>>>(yb, sums, sumsq, gamma, beta, out);
}